// Round 5
// baseline (365.417 us; speedup 1.0000x reference)
//
#include <hip/hip_runtime.h>

// IDWT 2D Haar synthesis, collapsed butterfly:
// input pixel (i,j) of {LL,LH,HL,HH} -> 2x2 output block at (2i,2j):
//   out[2i  ][2j] = .5(a+b+c+d)   out[2i  ][2j+1] = .5(a-b+c-d)
//   out[2i+1][2j] = .5(a+b-c-d)   out[2i+1][2j+1] = .5(a-b-c+d)
// Shapes: in (32,128,56,56) f32 each; out (32,128,112,112) f32.
// One thread per input float4 (4 pixels along j) -> 2 rows x 8 floats out.

typedef float f32x4 __attribute__((ext_vector_type(4)));  // clang vector: OK for NT builtins

#define H_IN   56
#define W4     14                    // 14 float4 per input row (56/4)
#define W_OUT  112
#define PLANE_OUT (112 * 112)        // 12544

__global__ __launch_bounds__(256) void idwt_haar_kernel(
    const float* __restrict__ LL, const float* __restrict__ LH,
    const float* __restrict__ HL, const float* __restrict__ HH,
    float* __restrict__ out, int total4)
{
    const int idx = blockIdx.x * 256 + threadIdx.x;   // one float4 of input
    if (idx >= total4) return;

    // idx = (bc*H_IN + i)*W4 + w4 ; flat input float offset = 4*idx
    const int w4   = idx % W4;
    const int rest = idx / W4;        // bc*H_IN + i
    const int i    = rest % H_IN;
    const int bc   = rest / H_IN;

    const f32x4 a = *reinterpret_cast<const f32x4*>(LL + 4 * idx);
    const f32x4 b = *reinterpret_cast<const f32x4*>(LH + 4 * idx);
    const f32x4 c = *reinterpret_cast<const f32x4*>(HL + 4 * idx);
    const f32x4 d = *reinterpret_cast<const f32x4*>(HH + 4 * idx);

    const f32x4 apc = a + c, amc = a - c;   // row 2i uses a+c, row 2i+1 uses a-c
    const f32x4 bpd = b + d, bmd = b - d;

    f32x4 r0a, r0b, r1a, r1b;
    // row 2i: interleave of (a+c) +/- (b+d)
    r0a.x = 0.5f * (apc.x + bpd.x);
    r0a.y = 0.5f * (apc.x - bpd.x);
    r0a.z = 0.5f * (apc.y + bpd.y);
    r0a.w = 0.5f * (apc.y - bpd.y);
    r0b.x = 0.5f * (apc.z + bpd.z);
    r0b.y = 0.5f * (apc.z - bpd.z);
    r0b.z = 0.5f * (apc.w + bpd.w);
    r0b.w = 0.5f * (apc.w - bpd.w);
    // row 2i+1: interleave of (a-c) +/- (b-d)
    r1a.x = 0.5f * (amc.x + bmd.x);
    r1a.y = 0.5f * (amc.x - bmd.x);
    r1a.z = 0.5f * (amc.y + bmd.y);
    r1a.w = 0.5f * (amc.y - bmd.y);
    r1b.x = 0.5f * (amc.z + bmd.z);
    r1b.y = 0.5f * (amc.z - bmd.z);
    r1b.z = 0.5f * (amc.w + bmd.w);
    r1b.w = 0.5f * (amc.w - bmd.w);

    const int out_base = bc * PLANE_OUT + (2 * i) * W_OUT + 8 * w4;
    f32x4* p0 = reinterpret_cast<f32x4*>(out + out_base);            // row 2i
    f32x4* p1 = reinterpret_cast<f32x4*>(out + out_base + W_OUT);    // row 2i+1
    __builtin_nontemporal_store(r0a, p0);
    __builtin_nontemporal_store(r0b, p0 + 1);
    __builtin_nontemporal_store(r1a, p1);
    __builtin_nontemporal_store(r1b, p1 + 1);
}

extern "C" void kernel_launch(void* const* d_in, const int* in_sizes, int n_in,
                              void* d_out, int out_size, void* d_ws, size_t ws_size,
                              hipStream_t stream) {
    const float* LL = (const float*)d_in[0];
    const float* LH = (const float*)d_in[1];
    const float* HL = (const float*)d_in[2];
    const float* HH = (const float*)d_in[3];
    float* out = (float*)d_out;

    const int total4 = in_sizes[0] / 4;               // 3,211,264 float4 elems
    const int blocks = (total4 + 255) / 256;          // 12544 (exact)

    idwt_haar_kernel<<<blocks, 256, 0, stream>>>(LL, LH, HL, HH, out, total4);
}